// Round 3
// baseline (112.209 us; speedup 1.0000x reference)
//
#include <hip/hip_runtime.h>
#include <math.h>

#define HH 28
#define WW 28
#define NPIX 784
#define MMAX 785
#define NMAXP 100
#define NTH 512
#define BCAP 512       // max basins (theory bound: H1 4-conn <= 393)
#define HSZ 2048
#define HMASK 2047
#define ECAP 2048      // deduped basin-pair edges (random ~470); max survivors = HSZ
#define PCAP 512
#define NBUCK 4096     // 12-bit weight buckets for the edge sort
// Essential-death sentinel: must stay FINITE after the harness's bf16
// round-trip (FLT_MAX rounds to +inf in bf16 -> inf-inf=NaN). 1e30 is safe.
#define ESS_DEATH 1e30f

template<int N> struct IC { static constexpr int v = N; };

// monotone float<->u32 (totally ordered as unsigned)
__device__ __forceinline__ unsigned f2mono(float f) {
    unsigned u = __float_as_uint(f);
    return (u & 0x80000000u) ? ~u : (u | 0x80000000u);
}
__device__ __forceinline__ float mono2f(unsigned m) {
    unsigned u = (m & 0x80000000u) ? (m ^ 0x80000000u) : ~m;
    return __uint_as_float(u);
}

// neighbors of cell c; nb[k] = -1 if invalid.
// which==0: 8-conn. which==1: 4-conn + virtual boundary node NPIX.
__device__ __forceinline__ int get_nbrs(int c, int which, int* nb) {
    int ci = c / WW;
    int cj = c - ci * WW;
    if (which == 0) {
        const int di[8] = {-1,-1,-1, 0, 0, 1, 1, 1};
        const int dj[8] = {-1, 0, 1,-1, 1,-1, 0, 1};
        #pragma unroll
        for (int k = 0; k < 8; ++k) {
            int ii = ci + di[k], jj = cj + dj[k];
            nb[k] = (ii >= 0 && ii < HH && jj >= 0 && jj < WW) ? (ii * WW + jj) : -1;
        }
        return 8;
    } else {
        const int di[4] = {-1, 1, 0, 0};
        const int dj[4] = { 0, 0,-1, 1};
        #pragma unroll
        for (int k = 0; k < 4; ++k) {
            int ii = ci + di[k], jj = cj + dj[k];
            nb[k] = (ii >= 0 && ii < HH && jj >= 0 && jj < WW) ? (ii * WW + jj) : -1;
        }
        nb[4] = (ci == 0 || ci == HH - 1 || cj == 0 || cj == WW - 1) ? NPIX : -1;
        return 5;
    }
}

// One block per (sample, dim): blk = s*2 + which.
// which==0 -> H0 (8-conn sublevel on x); which==1 -> H1 via superlevel
// (sublevel on -x, 4-conn, virtual -inf boundary node).
__global__ __launch_bounds__(NTH)
void pd_kernel(const float* __restrict__ x, float* __restrict__ out)
{
    const int blk   = blockIdx.x;
    const int s     = blk >> 1;
    const int which = blk & 1;
    const int tid   = threadIdx.x;
    const int lane  = tid & 63;
    const int M     = NPIX + which;

    __shared__ float vals[MMAX];
    __shared__ int   dA[MMAX];                  // steepest-descent pointer (ping)
    __shared__ int   dB[MMAX];                  // pointer (pong)
    __shared__ int   cido[MMAX];                // per-cell compact basin id
    __shared__ int   cmap[MMAX];                // root cell -> cid (value rank)
    __shared__ unsigned long long rootsU[BCAP]; // unsorted (valmono<<32)|cell, 64-padded
    __shared__ unsigned bval[BCAP];             // basin-min valmono per cid (= value rank)
    __shared__ unsigned hkey[HSZ];              // hash: pk+1 (0 = empty)
    __shared__ unsigned hval[HSZ];              // hash: min weight (monotone u32)
    __shared__ unsigned cnt[NBUCK];             // bucket counters (own array, init at start)
    __shared__ unsigned long long e2[ECAP];     // unsorted edges; then SORTED; then sel keys
    __shared__ unsigned long long e3[ECAP];     // bucket-grouped scratch
    __shared__ unsigned long long mrec[PCAP];   // raw merge records (wmono<<32)|y
    __shared__ float pb[PCAP], pdd[PCAP];       // recorded pairs (output space)
    __shared__ int   rsel[NMAXP];               // output slot -> pair index
    __shared__ int   bcnt, scnt, npairs;
    __shared__ int   wtot[NTH / 64], wbase2[NTH / 64];

    // rank of ki among arr[0..N64) (N64 = 64-multiple, padded with ~0ull;
    // distinct keys). Chunked: wave loads 64 keys coalesced, broadcasts via
    // readlane (unrolled -> constant lane), counts kjj < ki. No barriers.
    auto rankOf = [&](const unsigned long long* arr, int N64,
                      unsigned long long ki) -> int {
        int rk = 0;
        for (int base = 0; base < N64; base += 64) {
            unsigned long long kj = arr[base + lane];
            unsigned lo = (unsigned)kj, hi = (unsigned)(kj >> 32);
            #pragma unroll
            for (int t = 0; t < 64; ++t) {
                unsigned jlo = (unsigned)__builtin_amdgcn_readlane((int)lo, t);
                unsigned jhi = (unsigned)__builtin_amdgcn_readlane((int)hi, t);
                unsigned long long kjj = ((unsigned long long)jhi << 32) | jlo;
                rk += (kjj < ki) ? 1 : 0;
            }
        }
        return rk;
    };

    // ---- B1: init everything with no downstream ordering hazards ----
    if (tid == 0) { bcnt = 0; scnt = 0; npairs = 0; }
    if (tid < NMAXP) rsel[tid] = -1;
    for (int i = tid; i < HSZ; i += NTH) { hkey[i] = 0u; hval[i] = 0xFFFFFFFFu; }
    for (int i = tid; i < NBUCK; i += NTH) cnt[i] = 0u;
    for (int i = tid; i < NPIX; i += NTH) {
        float v = x[s * NPIX + i];
        vals[i] = which ? -v : v;
    }
    if (tid == 0 && which) vals[NPIX] = -INFINITY;
    __syncthreads();

    // ---- descent (lex-min over {self} U nbrs) + fused root collection ----
    unsigned long long rku0 = 0ull, rku1 = 0ull;
    int rc = 0;
    {   // cell i = tid (always < NPIX)
        int i = tid;
        int best = i; float bv = vals[i];
        int nb[8];
        int K = get_nbrs(i, which, nb);
        for (int k = 0; k < K; ++k) {
            int n = nb[k]; if (n < 0) continue;
            float vn = vals[n];
            if (vn < bv || (vn == bv && n < best)) { bv = vn; best = n; }
        }
        dA[i] = best;
        if (best == i) { rku0 = ((unsigned long long)f2mono(vals[i]) << 32) | (unsigned)i; rc = 1; }
    }
    {   // cell i = tid + NTH (may be the virtual node NPIX for H1)
        int i = NTH + tid;
        if (i < M) {
            int best = i; float bv = vals[i];
            if (i < NPIX) {
                int nb[8];
                int K = get_nbrs(i, which, nb);
                for (int k = 0; k < K; ++k) {
                    int n = nb[k]; if (n < 0) continue;
                    float vn = vals[n];
                    if (vn < bv || (vn == bv && n < best)) { bv = vn; best = n; }
                }
            }
            dA[i] = best;
            if (best == i) {
                unsigned long long kk = ((unsigned long long)f2mono(vals[i]) << 32) | (unsigned)i;
                if (rc) rku1 = kk; else rku0 = kk;
                ++rc;
            }
        }
    }
    {   // wave inclusive scan of rc -> one atomic per wave
        int sc = rc;
        #pragma unroll
        for (int d = 1; d < 64; d <<= 1) {
            int up = __shfl_up(sc, d, 64);
            if (lane >= d) sc += up;
        }
        int wtotal = __shfl(sc, 63, 64);
        int base = 0;
        if (lane == 0 && wtotal) base = atomicAdd(&bcnt, wtotal);
        base = __shfl(base, 0, 64);
        int off = base + sc - rc;
        if (rc > 0 && off < BCAP)     rootsU[off]     = rku0;
        if (rc > 1 && off + 1 < BCAP) rootsU[off + 1] = rku1;
    }
    __syncthreads();

    int B = bcnt; if (B > BCAP) B = BCAP;
    const int B64 = (B + 63) & ~63;
    for (int i = B + tid; i < B64; i += NTH) rootsU[i] = ~0ull;
    __syncthreads();

    // ---- cid = value rank of root (rank-by-count)  ||  doubling pass 1 ----
    for (int i = tid; i < B64; i += NTH) {
        unsigned long long ki = rootsU[i];
        int rk = rankOf(rootsU, B64, ki);
        if (i < B) {
            int cell = (int)(ki & 0xFFFFFFFFull);
            cmap[cell] = rk;
            bval[rk] = (unsigned)(ki >> 32);
        }
    }
    for (int i = tid; i < M; i += NTH) { int q = dA[i]; dB[i] = dA[q]; }
    __syncthreads();
    // ---- doubling pass 2 (pointers now stride 4) ----
    for (int i = tid; i < M; i += NTH) { int q = dB[i]; dA[i] = dB[q]; }
    __syncthreads();
    // ---- chase to root + cid assignment (no barriers inside) ----
    for (int i = tid; i < M; i += NTH) {
        int r = dA[i];
        int r2 = dA[r];
        while (r2 != r) { r = r2; r2 = dA[r]; }
        cido[i] = cmap[r];
    }
    __syncthreads();

    // ---- cross-basin edges -> hash dedup (min weight per basin pair) ----
    for (int c = tid; c < NPIX; c += NTH) {
        float vc = vals[c];
        int bc = cido[c];
        int nb[8];
        int K = get_nbrs(c, which, nb);
        unsigned wm = f2mono(vc);
        for (int k = 0; k < K; ++k) {
            int n = nb[k]; if (n < 0) continue;
            float vn = vals[n];
            if (!(vn < vc || (vn == vc && n < c))) continue;  // emit from higher endpoint
            int bn = cido[n];
            if (bn == bc) continue;
            unsigned c0 = (unsigned)(bc < bn ? bc : bn);
            unsigned c1 = (unsigned)(bc < bn ? bn : bc);
            unsigned pk  = (c0 << 9) | c1;       // cids < 512 -> 18 bits
            unsigned key = pk + 1u;
            unsigned slot = (pk * 0x9E3779B1u) >> 21;  // 11-bit hash
            for (;;) {
                unsigned prev = atomicCAS(&hkey[slot], 0u, key);
                if (prev == 0u || prev == key) { atomicMin(&hval[slot], wm); break; }
                slot = (slot + 1) & HMASK;
            }
        }
    }
    __syncthreads();

    // ---- gather survivors: 4 slots/thread, wave scan, 1 atomic/wave ----
    {
        unsigned k0 = hkey[tid],           k1 = hkey[tid + NTH],
                 k2 = hkey[tid + 2 * NTH], k3 = hkey[tid + 3 * NTH];
        unsigned v0 = hval[tid],           v1 = hval[tid + NTH],
                 v2 = hval[tid + 2 * NTH], v3 = hval[tid + 3 * NTH];
        int c = (k0 ? 1 : 0) + (k1 ? 1 : 0) + (k2 ? 1 : 0) + (k3 ? 1 : 0);
        int sc = c;
        #pragma unroll
        for (int d = 1; d < 64; d <<= 1) {
            int up = __shfl_up(sc, d, 64);
            if (lane >= d) sc += up;
        }
        int wtotal = __shfl(sc, 63, 64);
        int base = 0;
        if (lane == 0 && wtotal) base = atomicAdd(&scnt, wtotal);
        base = __shfl(base, 0, 64);
        int p = base + sc - c;
        if (k0) { e2[p] = ((unsigned long long)v0 << 18) | (unsigned long long)(k0 - 1u); ++p; }
        if (k1) { e2[p] = ((unsigned long long)v1 << 18) | (unsigned long long)(k1 - 1u); ++p; }
        if (k2) { e2[p] = ((unsigned long long)v2 << 18) | (unsigned long long)(k2 - 1u); ++p; }
        if (k3) { e2[p] = ((unsigned long long)v3 << 18) | (unsigned long long)(k3 - 1u); ++p; }
    }
    __syncthreads();
    const int S = scnt;                          // <= HSZ = ECAP, no overflow
    const int S64 = (S + 63) & ~63;

    // ---- deterministic bucket sort by weight ----
    // bucket = top 12 bits of wmono = key >> 38. count (cnt pre-zeroed at B1)
    // -> exclusive prefix -> grouped scatter -> exact in-bucket rank on full
    // 64-bit keys (distinct) -> final sorted order into e2.
    for (int i = S + tid; i < S64; i += NTH) e2[i] = ~0ull;  // pad for Kruskal reads
    for (int i = tid; i < S; i += NTH)
        atomicAdd(&cnt[(unsigned)(e2[i] >> 38)], 1u);
    __syncthreads();
    {   // exclusive prefix over NBUCK bins: 8/thread local + shfl wave scan
        unsigned c[8]; int loc = 0;
        #pragma unroll
        for (int k2 = 0; k2 < 8; ++k2) { c[k2] = cnt[tid * 8 + k2]; loc += (int)c[k2]; }
        int scan = loc;
        #pragma unroll
        for (int d = 1; d < 64; d <<= 1) {
            int up = __shfl_up(scan, d, 64);
            if (lane >= d) scan += up;
        }
        int wid = tid >> 6;
        if (lane == 63) wtot[wid] = scan;
        __syncthreads();
        if (tid == 0) {
            int acc = 0;
            #pragma unroll
            for (int w2 = 0; w2 < NTH / 64; ++w2) { wbase2[w2] = acc; acc += wtot[w2]; }
        }
        __syncthreads();
        int ex = wbase2[wid] + (scan - loc);
        #pragma unroll
        for (int k2 = 0; k2 < 8; ++k2) { cnt[tid * 8 + k2] = (unsigned)ex; ex += (int)c[k2]; }
    }
    __syncthreads();
    for (int i = tid; i < S; i += NTH) {
        unsigned long long k = e2[i];
        unsigned slot = atomicAdd(&cnt[(unsigned)(k >> 38)], 1u);
        e3[slot] = k;
    }
    __syncthreads();
    // after scatter: bucket b spans [cnt[b-1], cnt[b]) (cnt[-1] = 0)
    for (int i = tid; i < S; i += NTH) {
        unsigned long long ki = e3[i];
        int b = (int)(ki >> 38);
        int lo2 = (b == 0) ? 0 : (int)cnt[b - 1];
        int hi2 = (int)cnt[b];
        int rk = lo2;
        for (int j = lo2; j < hi2; ++j) rk += (e3[j] < ki) ? 1 : 0;
        e2[rk] = ki;
    }
    __syncthreads();

    // ---- serial Kruskal on wave 0 (reads SORTED e2): per-64-batch parallel
    //      root prefilter (ds_bpermute over register label planes; labels only
    //      coarsen, so la==lb at batch entry => edge can never merge => skip) +
    //      4-wide speculative serial resolution over candidates only +
    //      early exit after B-1 merges (connected => exactly B-1 merges). ----
    auto kruskal = [&](auto icreg) {
        constexpr int NREG = decltype(icreg)::v;
        int lab[NREG];
        #pragma unroll
        for (int r = 0; r < NREG; ++r) lab[r] = r * 64 + tid;
        int np = 0;
        const int target = B - 1;
        for (int base = 0; base < S && np < target; base += 64) {
            unsigned long long ecache = e2[base + tid];      // base mult of 64, tid<64
            unsigned eklo = (unsigned)ecache;
            unsigned ehiw = (unsigned)(ecache >> 32);
            unsigned pkL  = eklo & 0x3FFFFu;
            unsigned raaL = pkL >> 9, rbbL = pkL & 511u;
            // parallel batch-entry root lookup for all 64 edges
            int bpa[NREG], bpb[NREG];
            int aA = (int)((raaL & 63u) << 2);
            int aB = (int)((rbbL & 63u) << 2);
            #pragma unroll
            for (int r = 0; r < NREG; ++r) {
                bpa[r] = __builtin_amdgcn_ds_bpermute(aA, lab[r]);
                bpb[r] = __builtin_amdgcn_ds_bpermute(aB, lab[r]);
            }
            int la0, lb0;
            {
                unsigned sA = raaL >> 6, sB = rbbL >> 6;
                if constexpr (NREG == 2) {
                    la0 = (sA & 1) ? bpa[1] : bpa[0];
                    lb0 = (sB & 1) ? bpb[1] : bpb[0];
                } else if constexpr (NREG == 4) {
                    int x0 = (sA & 1) ? bpa[1] : bpa[0];
                    int x1 = (sA & 1) ? bpa[3] : bpa[2];
                    la0 = (sA & 2) ? x1 : x0;
                    int y0 = (sB & 1) ? bpb[1] : bpb[0];
                    int y1 = (sB & 1) ? bpb[3] : bpb[2];
                    lb0 = (sB & 2) ? y1 : y0;
                } else {
                    int x0 = (sA & 1) ? bpa[1] : bpa[0];
                    int x1 = (sA & 1) ? bpa[3] : bpa[2];
                    int x2 = (sA & 1) ? bpa[5] : bpa[4];
                    int x3 = (sA & 1) ? bpa[7] : bpa[6];
                    int x4 = (sA & 2) ? x1 : x0;
                    int x5 = (sA & 2) ? x3 : x2;
                    la0 = (sA & 4) ? x5 : x4;
                    int y0 = (sB & 1) ? bpb[1] : bpb[0];
                    int y1 = (sB & 1) ? bpb[3] : bpb[2];
                    int y2 = (sB & 1) ? bpb[5] : bpb[4];
                    int y3 = (sB & 1) ? bpb[7] : bpb[6];
                    int y4 = (sB & 2) ? y1 : y0;
                    int y5 = (sB & 2) ? y3 : y2;
                    lb0 = (sB & 4) ? y5 : y4;
                }
            }
            bool isc = ((base + tid) < S) && (la0 != lb0);
            unsigned long long m = __ballot(isc);
            while (m != 0ull && np < target) {
                unsigned klo[4]; int lnt[4], la[4], lb[4]; bool act[4];
                #pragma unroll
                for (int t = 0; t < 4; ++t) {
                    act[t] = (m != 0ull);
                    int ln = act[t] ? (int)__builtin_ctzll(m) : 0;
                    if (act[t]) m &= (m - 1ull);
                    lnt[t] = ln;
                    klo[t] = (unsigned)__builtin_amdgcn_readlane((int)eklo, ln);
                    unsigned pk  = klo[t] & 0x3FFFFu;
                    unsigned raa = pk >> 9, rbb = pk & 511u;
                    int sa = (int)(raa >> 6), sb = (int)(rbb >> 6);
                    asm volatile("" : "+v"(sa), "+v"(sb));   // force cndmask tree
                    int g1, g2;
                    if constexpr (NREG == 2) {
                        g1 = (sa & 1) ? lab[1] : lab[0];
                        g2 = (sb & 1) ? lab[1] : lab[0];
                    } else if constexpr (NREG == 4) {
                        int a1 = (sa & 1) ? lab[1] : lab[0];
                        int b1 = (sa & 1) ? lab[3] : lab[2];
                        g1 = (sa & 2) ? b1 : a1;
                        int a2 = (sb & 1) ? lab[1] : lab[0];
                        int b2 = (sb & 1) ? lab[3] : lab[2];
                        g2 = (sb & 2) ? b2 : a2;
                    } else {
                        int a1 = (sa & 1) ? lab[1] : lab[0];
                        int b1 = (sa & 1) ? lab[3] : lab[2];
                        int c1 = (sa & 1) ? lab[5] : lab[4];
                        int d1 = (sa & 1) ? lab[7] : lab[6];
                        int e1 = (sa & 2) ? b1 : a1;
                        int f1 = (sa & 2) ? d1 : c1;
                        g1 = (sa & 4) ? f1 : e1;
                        int a2 = (sb & 1) ? lab[1] : lab[0];
                        int b2 = (sb & 1) ? lab[3] : lab[2];
                        int c2 = (sb & 1) ? lab[5] : lab[4];
                        int d2 = (sb & 1) ? lab[7] : lab[6];
                        int e2v = (sb & 2) ? b2 : a2;
                        int f2 = (sb & 2) ? d2 : c2;
                        g2 = (sb & 4) ? f2 : e2v;
                    }
                    la[t] = __builtin_amdgcn_readlane(g1, (int)(raa & 63u));
                    lb[t] = __builtin_amdgcn_readlane(g2, (int)(rbb & 63u));
                    if (!act[t]) { la[t] = 0; lb[t] = 0; }   // no-op slot
                }
                int ys[4], es[4];
                #pragma unroll
                for (int t = 0; t < 4; ++t) {
                    int A = la[t], Bv = lb[t];
                    #pragma unroll
                    for (int k = 0; k < t; ++k) {
                        A  = (A  == ys[k]) ? es[k] : A;
                        Bv = (Bv == ys[k]) ? es[k] : Bv;
                    }
                    int mn = A < Bv ? A : Bv;
                    int mx = A ^ Bv ^ mn;
                    es[t] = mn;
                    ys[t] = (A != Bv) ? mx : -1;
                }
                #pragma unroll
                for (int t = 0; t < 4; ++t) {
                    if (ys[t] >= 0) {
                        unsigned khit = (unsigned)__builtin_amdgcn_readlane(
                            (int)ehiw, lnt[t]);
                        unsigned w = (klo[t] >> 18) | (khit << 14);
                        if (tid == 0 && np < PCAP)
                            mrec[np] = ((unsigned long long)w << 32) | (unsigned)ys[t];
                        ++np;
                        #pragma unroll
                        for (int r = 0; r < NREG; ++r)
                            lab[r] = (lab[r] == ys[t]) ? es[t] : lab[r];
                    }
                }
            }
        }
        if (tid == 0) npairs = (np < PCAP) ? np : PCAP;
    };
    if (tid < 64 && S > 0) {
        if (B <= 128)      kruskal(IC<2>{});
        else if (B <= 256) kruskal(IC<4>{});
        else               kruskal(IC<8>{});
    }
    __syncthreads();
    const int P = npairs;
    const int P64 = (P + 63) & ~63;

    // ---- materialize pairs + build selection keys (pers desc, idx asc) ----
    for (int i = tid; i < P64; i += NTH) {
        unsigned long long kk2 = ~0ull;
        if (i < P) {
            unsigned long long m = mrec[i];
            int y = (int)(m & 0xFFFFFFFFull);
            float w  = mono2f((unsigned)(m >> 32));
            float bf = mono2f(bval[y]);
            float b, d;
            if (which == 0) { b = bf; d = w; }
            else            { b = -w; d = -bf; }
            pb[i] = b; pdd[i] = d;
            unsigned pm = __float_as_uint(d - b);   // pers > 0 -> monotone bits
            kk2 = ((unsigned long long)(~pm) << 32) | (unsigned)i;
        }
        e2[i] = kk2;
    }
    __syncthreads();

    // ---- top-NMAXP by rank-by-count ----
    const int off = (which == 0) ? 1 : 0;          // H0 slot 0 = essential pair
    for (int i = tid; i < P64; i += NTH) {
        unsigned long long ki = e2[i];
        int rk = rankOf(e2, P64, ki);
        if (i < P && rk < NMAXP - off) rsel[rk + off] = i;
    }
    __syncthreads();

    // ---- write diagram: [32, 2, 100, 2] ----
    float* o = out + (size_t)blk * NMAXP * 2;
    if (tid < NMAXP) {
        float b = 0.f, d = 0.f;
        if (which == 0 && tid == 0) { b = mono2f(bval[0]); d = ESS_DEATH; }
        else {
            int q = rsel[tid];
            if (q >= 0) { b = pb[q]; d = pdd[q]; }
        }
        o[tid * 2]     = b;
        o[tid * 2 + 1] = d;
    }
}

extern "C" void kernel_launch(void* const* d_in, const int* in_sizes, int n_in,
                              void* d_out, int out_size, void* d_ws, size_t ws_size,
                              hipStream_t stream) {
    (void)in_sizes; (void)n_in; (void)out_size; (void)d_ws; (void)ws_size;
    const float* x = (const float*)d_in[0];
    float* out = (float*)d_out;
    pd_kernel<<<dim3(64), dim3(NTH), 0, stream>>>(x, out);
}

// Round 4
// 97.561 us; speedup vs baseline: 1.1501x; 1.1501x over previous
//
#include <hip/hip_runtime.h>
#include <math.h>

#define HH 28
#define WW 28
#define NPIX 784
#define MMAX 785
#define NMAXP 100
#define NTH 512
#define BCAP 512       // max basins (theory bound: H1 4-conn <= 393)
#define HSZ 2048
#define HMASK 2047
#define ECAP 2048      // deduped basin-pair edges (random ~470); max survivors = HSZ
#define PCAP 512
#define JMAXP 10       // 2^10 >= 785 worst-case descent depth
#define NBUCK 4096     // 12-bit weight buckets for the edge sort (= 2*HSZ, aliases hash)
// Essential-death sentinel: must stay FINITE after the harness's bf16
// round-trip (FLT_MAX rounds to +inf in bf16 -> inf-inf=NaN). 1e30 is safe.
#define ESS_DEATH 1e30f

template<int N> struct IC { static constexpr int v = N; };

// monotone float<->u32 (totally ordered as unsigned)
__device__ __forceinline__ unsigned f2mono(float f) {
    unsigned u = __float_as_uint(f);
    return (u & 0x80000000u) ? ~u : (u | 0x80000000u);
}
__device__ __forceinline__ float mono2f(unsigned m) {
    unsigned u = (m & 0x80000000u) ? (m ^ 0x80000000u) : ~m;
    return __uint_as_float(u);
}

// neighbors of cell c; nb[k] = -1 if invalid.
// which==0: 8-conn. which==1: 4-conn + virtual boundary node NPIX.
__device__ __forceinline__ int get_nbrs(int c, int which, int* nb) {
    int ci = c / WW;
    int cj = c - ci * WW;
    if (which == 0) {
        const int di[8] = {-1,-1,-1, 0, 0, 1, 1, 1};
        const int dj[8] = {-1, 0, 1,-1, 1,-1, 0, 1};
        #pragma unroll
        for (int k = 0; k < 8; ++k) {
            int ii = ci + di[k], jj = cj + dj[k];
            nb[k] = (ii >= 0 && ii < HH && jj >= 0 && jj < WW) ? (ii * WW + jj) : -1;
        }
        return 8;
    } else {
        const int di[4] = {-1, 1, 0, 0};
        const int dj[4] = { 0, 0,-1, 1};
        #pragma unroll
        for (int k = 0; k < 4; ++k) {
            int ii = ci + di[k], jj = cj + dj[k];
            nb[k] = (ii >= 0 && ii < HH && jj >= 0 && jj < WW) ? (ii * WW + jj) : -1;
        }
        nb[4] = (ci == 0 || ci == HH - 1 || cj == 0 || cj == WW - 1) ? NPIX : -1;
        return 5;
    }
}

// One block per (sample, dim): blk = s*2 + which.
// which==0 -> H0 (8-conn sublevel on x); which==1 -> H1 via superlevel
// (sublevel on -x, 4-conn, virtual -inf boundary node).
__global__ __launch_bounds__(NTH)
void pd_kernel(const float* __restrict__ x, float* __restrict__ out)
{
    const int blk   = blockIdx.x;
    const int s     = blk >> 1;
    const int which = blk & 1;
    const int tid   = threadIdx.x;
    const int lane  = tid & 63;
    const int M     = NPIX + which;

    __shared__ float vals[MMAX];
    __shared__ int   dA[MMAX];                  // steepest-descent pointer (ping)
    __shared__ int   dB[MMAX];                  // pointer (pong)
    __shared__ int   cido[MMAX];                // per-cell compact basin id
    __shared__ unsigned long long rootsU[BCAP]; // unsorted (valmono<<32)|cell, 64-padded
    __shared__ unsigned bval[BCAP];             // basin-min valmono per cid (= value rank)
    __shared__ unsigned hpool[2 * HSZ];         // hash key|val; reused as sort cnt[NBUCK]
    __shared__ unsigned long long e2[ECAP];     // unsorted edges; then SORTED; then sel keys
    __shared__ unsigned long long e3[ECAP];     // bucket-grouped scratch
    __shared__ unsigned long long mrec[PCAP];   // raw merge records (wmono<<32)|y
    __shared__ float pb[PCAP], pdd[PCAP];       // recorded pairs (output space)
    __shared__ int   rsel[NMAXP];               // output slot -> pair index
    __shared__ int   bcnt, scnt, npairs;
    __shared__ int   jflag[JMAXP + 1];
    __shared__ int   wtot[NTH / 64], wbase2[NTH / 64];

    unsigned* const hkey = hpool;               // hash: pk+1 (0 = empty)
    unsigned* const hval = hpool + HSZ;         // hash: min weight (monotone u32)
    unsigned* const cnt  = hpool;               // sort: NBUCK bucket counters (hash is dead)

    // rank of ki among arr[0..N64) (N64 = 64-multiple, padded with ~0ull;
    // distinct keys). Chunked: wave loads 64 keys coalesced, broadcasts via
    // readlane (unrolled -> constant lane), counts kjj < ki. No barriers.
    auto rankOf = [&](const unsigned long long* arr, int N64,
                      unsigned long long ki) -> int {
        int rk = 0;
        for (int base = 0; base < N64; base += 64) {
            unsigned long long kj = arr[base + lane];
            unsigned lo = (unsigned)kj, hi = (unsigned)(kj >> 32);
            #pragma unroll
            for (int t = 0; t < 64; ++t) {
                unsigned jlo = (unsigned)__builtin_amdgcn_readlane((int)lo, t);
                unsigned jhi = (unsigned)__builtin_amdgcn_readlane((int)hi, t);
                unsigned long long kjj = ((unsigned long long)jhi << 32) | jlo;
                rk += (kjj < ki) ? 1 : 0;
            }
        }
        return rk;
    };

    if (tid == 0) { bcnt = 0; scnt = 0; npairs = 0; }
    if (tid < JMAXP + 1) jflag[tid] = 0;
    for (int i = tid; i < HSZ; i += NTH) { hkey[i] = 0u; hval[i] = 0xFFFFFFFFu; }
    for (int i = tid; i < NPIX; i += NTH) {
        float v = x[s * NPIX + i];
        vals[i] = which ? -v : v;
    }
    if (tid == 0 && which) vals[NPIX] = -INFINITY;
    __syncthreads();

    // ---- descent (lex-min over {self} U nbrs) + fused root collection ----
    unsigned long long rku0 = 0ull, rku1 = 0ull;
    int rc = 0;
    {   // cell i = tid (always < NPIX)
        int i = tid;
        int best = i; float bv = vals[i];
        int nb[8];
        int K = get_nbrs(i, which, nb);
        for (int k = 0; k < K; ++k) {
            int n = nb[k]; if (n < 0) continue;
            float vn = vals[n];
            if (vn < bv || (vn == bv && n < best)) { bv = vn; best = n; }
        }
        dA[i] = best;
        if (best == i) { rku0 = ((unsigned long long)f2mono(vals[i]) << 32) | (unsigned)i; rc = 1; }
    }
    {   // cell i = tid + NTH (may be the virtual node NPIX for H1)
        int i = NTH + tid;
        if (i < M) {
            int best = i; float bv = vals[i];
            if (i < NPIX) {
                int nb[8];
                int K = get_nbrs(i, which, nb);
                for (int k = 0; k < K; ++k) {
                    int n = nb[k]; if (n < 0) continue;
                    float vn = vals[n];
                    if (vn < bv || (vn == bv && n < best)) { bv = vn; best = n; }
                }
            }
            dA[i] = best;
            if (best == i) {
                unsigned long long kk = ((unsigned long long)f2mono(vals[i]) << 32) | (unsigned)i;
                if (rc) rku1 = kk; else rku0 = kk;
                ++rc;
            }
        }
    }
    {   // wave inclusive scan of rc -> one atomic per wave
        int sc = rc;
        #pragma unroll
        for (int d = 1; d < 64; d <<= 1) {
            int up = __shfl_up(sc, d, 64);
            if (lane >= d) sc += up;
        }
        int wtotal = __shfl(sc, 63, 64);
        int base = 0;
        if (lane == 0 && wtotal) base = atomicAdd(&bcnt, wtotal);
        base = __shfl(base, 0, 64);
        int off = base + sc - rc;
        if (rc > 0 && off < BCAP)     rootsU[off]     = rku0;
        if (rc > 1 && off + 1 < BCAP) rootsU[off + 1] = rku1;
    }
    __syncthreads();

    int B = bcnt; if (B > BCAP) B = BCAP;
    const int B64 = (B + 63) & ~63;
    // pad rootsU inside the first jumping phase (read only after next barrier)
    for (int i = B + tid; i < B64; i += NTH) rootsU[i] = ~0ull;

    // ---- pointer jumping: ping-pong doubling with exact early exit ----
    int* rootArr = dA;
    {
        int* src = dA;
        int* dst = dB;
        for (int pass = 0; pass < JMAXP; ++pass) {
            bool changed = false;
            for (int i = tid; i < M; i += NTH) {
                int q0 = src[i];
                int q1 = src[q0];
                dst[i] = q1;
                changed |= (q1 != q0);
            }
            unsigned long long mk = __ballot(changed);
            if (lane == 0 && mk) jflag[pass] = 1;   // benign race: all store 1
            __syncthreads();
            rootArr = dst;
            if (!jflag[pass]) break;
            int* tmp = src; src = dst; dst = tmp;
        }
    }
    int* cidmap = (rootArr == dA) ? dB : dA;   // scratch that won't clobber rootArr

    // ---- cid = value rank of root (rank-by-count) ----
    for (int i = tid; i < B64; i += NTH) {
        unsigned long long ki = rootsU[i];
        int rk = rankOf(rootsU, B64, ki);
        if (i < B) {
            int cell = (int)(ki & 0xFFFFFFFFull);
            cidmap[cell] = rk;
            bval[rk] = (unsigned)(ki >> 32);
        }
    }
    __syncthreads();
    for (int i = tid; i < M; i += NTH) cido[i] = cidmap[rootArr[i]];
    __syncthreads();

    // ---- cross-basin edges -> hash dedup (min weight per basin pair) ----
    for (int c = tid; c < NPIX; c += NTH) {
        float vc = vals[c];
        int bc = cido[c];
        int nb[8];
        int K = get_nbrs(c, which, nb);
        unsigned wm = f2mono(vc);
        for (int k = 0; k < K; ++k) {
            int n = nb[k]; if (n < 0) continue;
            float vn = vals[n];
            if (!(vn < vc || (vn == vc && n < c))) continue;  // emit from higher endpoint
            int bn = cido[n];
            if (bn == bc) continue;
            unsigned c0 = (unsigned)(bc < bn ? bc : bn);
            unsigned c1 = (unsigned)(bc < bn ? bn : bc);
            unsigned pk  = (c0 << 9) | c1;       // cids < 512 -> 18 bits
            unsigned key = pk + 1u;
            unsigned slot = (pk * 0x9E3779B1u) >> 21;  // 11-bit hash
            for (;;) {
                unsigned prev = atomicCAS(&hkey[slot], 0u, key);
                if (prev == 0u || prev == key) { atomicMin(&hval[slot], wm); break; }
                slot = (slot + 1) & HMASK;
            }
        }
    }
    __syncthreads();

    // ---- gather survivors: 4 slots/thread, wave scan, 1 atomic/wave ----
    {
        unsigned k0 = hkey[tid],           k1 = hkey[tid + NTH],
                 k2 = hkey[tid + 2 * NTH], k3 = hkey[tid + 3 * NTH];
        unsigned v0 = hval[tid],           v1 = hval[tid + NTH],
                 v2 = hval[tid + 2 * NTH], v3 = hval[tid + 3 * NTH];
        int c = (k0 ? 1 : 0) + (k1 ? 1 : 0) + (k2 ? 1 : 0) + (k3 ? 1 : 0);
        int sc = c;
        #pragma unroll
        for (int d = 1; d < 64; d <<= 1) {
            int up = __shfl_up(sc, d, 64);
            if (lane >= d) sc += up;
        }
        int wtotal = __shfl(sc, 63, 64);
        int base = 0;
        if (lane == 0 && wtotal) base = atomicAdd(&scnt, wtotal);
        base = __shfl(base, 0, 64);
        int p = base + sc - c;
        if (k0) { e2[p] = ((unsigned long long)v0 << 18) | (unsigned long long)(k0 - 1u); ++p; }
        if (k1) { e2[p] = ((unsigned long long)v1 << 18) | (unsigned long long)(k1 - 1u); ++p; }
        if (k2) { e2[p] = ((unsigned long long)v2 << 18) | (unsigned long long)(k2 - 1u); ++p; }
        if (k3) { e2[p] = ((unsigned long long)v3 << 18) | (unsigned long long)(k3 - 1u); ++p; }
    }
    __syncthreads();
    const int S = scnt;                          // <= HSZ = ECAP, no overflow
    const int S64 = (S + 63) & ~63;

    // ---- deterministic bucket sort by weight (O(S) passes) ----
    // bucket = top 12 bits of wmono = key >> 38. count -> exclusive prefix ->
    // grouped scatter (atomic order) -> exact in-bucket rank on full 64-bit
    // keys (distinct -> order independent of atomic timing) -> sorted e2.
    for (int i = tid; i < NBUCK; i += NTH) cnt[i] = 0u;   // hash is dead; reuse
    for (int i = S + tid; i < S64; i += NTH) { e2[i] = ~0ull; e3[i] = ~0ull; }
    __syncthreads();
    for (int i = tid; i < S; i += NTH)
        atomicAdd(&cnt[(unsigned)(e2[i] >> 38)], 1u);
    __syncthreads();
    {   // exclusive prefix over NBUCK bins: 8/thread local + shfl wave scan
        unsigned c[8]; int loc = 0;
        #pragma unroll
        for (int k2 = 0; k2 < 8; ++k2) { c[k2] = cnt[tid * 8 + k2]; loc += (int)c[k2]; }
        int scan = loc;
        #pragma unroll
        for (int d = 1; d < 64; d <<= 1) {
            int up = __shfl_up(scan, d, 64);
            if (lane >= d) scan += up;
        }
        int wid = tid >> 6;
        if (lane == 63) wtot[wid] = scan;
        __syncthreads();
        if (tid == 0) {
            int acc = 0;
            #pragma unroll
            for (int w2 = 0; w2 < NTH / 64; ++w2) { wbase2[w2] = acc; acc += wtot[w2]; }
        }
        __syncthreads();
        int ex = wbase2[wid] + (scan - loc);
        #pragma unroll
        for (int k2 = 0; k2 < 8; ++k2) { cnt[tid * 8 + k2] = (unsigned)ex; ex += (int)c[k2]; }
    }
    __syncthreads();
    for (int i = tid; i < S; i += NTH) {
        unsigned long long k = e2[i];
        unsigned slot = atomicAdd(&cnt[(unsigned)(k >> 38)], 1u);
        e3[slot] = k;
    }
    __syncthreads();
    // after scatter: bucket b spans [cnt[b-1], cnt[b]) (cnt[-1] = 0)
    for (int i = tid; i < S; i += NTH) {
        unsigned long long ki = e3[i];
        int b = (int)(ki >> 38);
        int lo2 = (b == 0) ? 0 : (int)cnt[b - 1];
        int hi2 = (int)cnt[b];
        int rk = lo2;
        for (int j = lo2; j < hi2; ++j) rk += (e3[j] < ki) ? 1 : 0;
        e2[rk] = ki;
    }
    __syncthreads();

    // ---- serial Kruskal on wave 0 (reads SORTED e2) ----
    // B <= 256 fast path: labels byte-PACKED, one 32-bit reg/lane
    // (byte j = label of basin j*64+lane). Lookup = 1 readlane + SALU
    // shift/mask (kills the cndmask select tree). Merge update = carry-safe
    // packed zero-byte detect. Prefilter: 1 ds_bpermute per endpoint.
    // Early exit after B-1 merges (connected => exactly B-1 merges).
    auto kruskalP = [&]() {
        unsigned pl = (unsigned)tid | ((unsigned)(64 + tid) << 8)
                    | ((unsigned)(128 + tid) << 16) | ((unsigned)(192 + tid) << 24);
        int np = 0;
        const int target = B - 1;
        for (int base = 0; base < S && np < target; base += 64) {
            unsigned long long ecache = e2[base + tid];      // base mult of 64, tid<64
            unsigned eklo = (unsigned)ecache;
            unsigned ehiw = (unsigned)(ecache >> 32);
            unsigned pkL  = eklo & 0x3FFFFu;
            unsigned raaL = pkL >> 9, rbbL = pkL & 511u;     // < 256 here
            int bpa = __builtin_amdgcn_ds_bpermute((int)((raaL & 63u) << 2), (int)pl);
            int bpb = __builtin_amdgcn_ds_bpermute((int)((rbbL & 63u) << 2), (int)pl);
            unsigned la0 = ((unsigned)bpa >> ((raaL >> 6) * 8)) & 0xFFu;
            unsigned lb0 = ((unsigned)bpb >> ((rbbL >> 6) * 8)) & 0xFFu;
            bool isc = ((base + tid) < S) && (la0 != lb0);
            unsigned long long m = __ballot(isc);
            while (m != 0ull && np < target) {
                unsigned klo[4]; int lnt[4]; unsigned la[4], lb[4]; bool act[4];
                #pragma unroll
                for (int t = 0; t < 4; ++t) {
                    act[t] = (m != 0ull);
                    int ln = act[t] ? (int)__builtin_ctzll(m) : 0;
                    if (act[t]) m &= (m - 1ull);
                    lnt[t] = ln;
                    klo[t] = (unsigned)__builtin_amdgcn_readlane((int)eklo, ln);
                    unsigned pk  = klo[t] & 0x3FFFFu;
                    unsigned raa = pk >> 9, rbb = pk & 511u;  // uniform scalars
                    unsigned kra = (unsigned)__builtin_amdgcn_readlane((int)pl, (int)(raa & 63u));
                    unsigned krb = (unsigned)__builtin_amdgcn_readlane((int)pl, (int)(rbb & 63u));
                    la[t] = (kra >> ((raa >> 6) * 8)) & 0xFFu;   // uniform -> SALU
                    lb[t] = (krb >> ((rbb >> 6) * 8)) & 0xFFu;
                    if (!act[t]) { la[t] = 0; lb[t] = 0; }       // no-op slot
                }
                unsigned ys[4], es[4];
                #pragma unroll
                for (int t = 0; t < 4; ++t) {
                    unsigned A = la[t], Bv = lb[t];
                    #pragma unroll
                    for (int k = 0; k < t; ++k) {
                        A  = (A  == ys[k]) ? es[k] : A;
                        Bv = (Bv == ys[k]) ? es[k] : Bv;
                    }
                    unsigned mn = A < Bv ? A : Bv;
                    unsigned mx = A ^ Bv ^ mn;
                    es[t] = mn;
                    ys[t] = (A != Bv) ? mx : 0xFFFFFFFFu;   // sentinel: no merge
                }
                #pragma unroll
                for (int t = 0; t < 4; ++t) {
                    if (ys[t] != 0xFFFFFFFFu) {
                        unsigned khit = (unsigned)__builtin_amdgcn_readlane(
                            (int)ehiw, lnt[t]);
                        unsigned w = (klo[t] >> 18) | (khit << 14);
                        if (tid == 0 && np < PCAP)
                            mrec[np] = ((unsigned long long)w << 32)
                                     | (unsigned long long)ys[t];
                        ++np;
                        // packed byte replace: bytes of pl equal to y -> e
                        unsigned yr  = ys[t] * 0x01010101u;
                        unsigned xr  = (ys[t] ^ es[t]) * 0x01010101u;
                        unsigned mm  = pl ^ yr;                          // 0-byte = match
                        unsigned nz  = ((mm & 0x7F7F7F7Fu) + 0x7F7F7F7Fu) | mm;
                        unsigned tz  = ~nz & 0x80808080u;                // 0x80 at matches
                        unsigned msk = tz | (tz - (tz >> 7));            // 0xFF at matches
                        pl ^= (xr & msk);
                    }
                }
            }
        }
        if (tid == 0) npairs = (np < PCAP) ? np : PCAP;
    };

    // fallback for 256 < B <= 512: striped labels in 8 regs (as before)
    auto kruskal = [&](auto icreg) {
        constexpr int NREG = decltype(icreg)::v;
        int lab[NREG];
        #pragma unroll
        for (int r = 0; r < NREG; ++r) lab[r] = r * 64 + tid;
        int np = 0;
        const int target = B - 1;
        for (int base = 0; base < S && np < target; base += 64) {
            unsigned long long ecache = e2[base + tid];
            unsigned eklo = (unsigned)ecache;
            unsigned ehiw = (unsigned)(ecache >> 32);
            unsigned pkL  = eklo & 0x3FFFFu;
            unsigned raaL = pkL >> 9, rbbL = pkL & 511u;
            int bpa[NREG], bpb[NREG];
            int aA = (int)((raaL & 63u) << 2);
            int aB = (int)((rbbL & 63u) << 2);
            #pragma unroll
            for (int r = 0; r < NREG; ++r) {
                bpa[r] = __builtin_amdgcn_ds_bpermute(aA, lab[r]);
                bpb[r] = __builtin_amdgcn_ds_bpermute(aB, lab[r]);
            }
            int la0, lb0;
            {
                unsigned sA = raaL >> 6, sB = rbbL >> 6;
                int x0 = (sA & 1) ? bpa[1] : bpa[0];
                int x1 = (sA & 1) ? bpa[3] : bpa[2];
                int x2 = (sA & 1) ? bpa[5] : bpa[4];
                int x3 = (sA & 1) ? bpa[7] : bpa[6];
                int x4 = (sA & 2) ? x1 : x0;
                int x5 = (sA & 2) ? x3 : x2;
                la0 = (sA & 4) ? x5 : x4;
                int y0 = (sB & 1) ? bpb[1] : bpb[0];
                int y1 = (sB & 1) ? bpb[3] : bpb[2];
                int y2 = (sB & 1) ? bpb[5] : bpb[4];
                int y3 = (sB & 1) ? bpb[7] : bpb[6];
                int y4 = (sB & 2) ? y1 : y0;
                int y5 = (sB & 2) ? y3 : y2;
                lb0 = (sB & 4) ? y5 : y4;
            }
            bool isc = ((base + tid) < S) && (la0 != lb0);
            unsigned long long m = __ballot(isc);
            while (m != 0ull && np < target) {
                unsigned klo[4]; int lnt[4], la[4], lb[4]; bool act[4];
                #pragma unroll
                for (int t = 0; t < 4; ++t) {
                    act[t] = (m != 0ull);
                    int ln = act[t] ? (int)__builtin_ctzll(m) : 0;
                    if (act[t]) m &= (m - 1ull);
                    lnt[t] = ln;
                    klo[t] = (unsigned)__builtin_amdgcn_readlane((int)eklo, ln);
                    unsigned pk  = klo[t] & 0x3FFFFu;
                    unsigned raa = pk >> 9, rbb = pk & 511u;
                    int sa = (int)(raa >> 6), sb = (int)(rbb >> 6);
                    asm volatile("" : "+v"(sa), "+v"(sb));   // force cndmask tree
                    int a1 = (sa & 1) ? lab[1] : lab[0];
                    int b1 = (sa & 1) ? lab[3] : lab[2];
                    int c1 = (sa & 1) ? lab[5] : lab[4];
                    int d1 = (sa & 1) ? lab[7] : lab[6];
                    int e1 = (sa & 2) ? b1 : a1;
                    int f1 = (sa & 2) ? d1 : c1;
                    int g1 = (sa & 4) ? f1 : e1;
                    int a2 = (sb & 1) ? lab[1] : lab[0];
                    int b2 = (sb & 1) ? lab[3] : lab[2];
                    int c2 = (sb & 1) ? lab[5] : lab[4];
                    int d2 = (sb & 1) ? lab[7] : lab[6];
                    int e2v = (sb & 2) ? b2 : a2;
                    int f2 = (sb & 2) ? d2 : c2;
                    int g2 = (sb & 4) ? f2 : e2v;
                    la[t] = __builtin_amdgcn_readlane(g1, (int)(raa & 63u));
                    lb[t] = __builtin_amdgcn_readlane(g2, (int)(rbb & 63u));
                    if (!act[t]) { la[t] = 0; lb[t] = 0; }
                }
                int ys[4], es[4];
                #pragma unroll
                for (int t = 0; t < 4; ++t) {
                    int A = la[t], Bv = lb[t];
                    #pragma unroll
                    for (int k = 0; k < t; ++k) {
                        A  = (A  == ys[k]) ? es[k] : A;
                        Bv = (Bv == ys[k]) ? es[k] : Bv;
                    }
                    int mn = A < Bv ? A : Bv;
                    int mx = A ^ Bv ^ mn;
                    es[t] = mn;
                    ys[t] = (A != Bv) ? mx : -1;
                }
                #pragma unroll
                for (int t = 0; t < 4; ++t) {
                    if (ys[t] >= 0) {
                        unsigned khit = (unsigned)__builtin_amdgcn_readlane(
                            (int)ehiw, lnt[t]);
                        unsigned w = (klo[t] >> 18) | (khit << 14);
                        if (tid == 0 && np < PCAP)
                            mrec[np] = ((unsigned long long)w << 32) | (unsigned)ys[t];
                        ++np;
                        #pragma unroll
                        for (int r = 0; r < NREG; ++r)
                            lab[r] = (lab[r] == ys[t]) ? es[t] : lab[r];
                    }
                }
            }
        }
        if (tid == 0) npairs = (np < PCAP) ? np : PCAP;
    };

    if (tid < 64 && S > 0) {
        if (B <= 256) kruskalP();
        else          kruskal(IC<8>{});
    }
    __syncthreads();
    const int P = npairs;
    const int P64 = (P + 63) & ~63;

    // ---- materialize pairs + build selection keys (pers desc, idx asc) ----
    for (int i = tid; i < P64; i += NTH) {
        unsigned long long kk2 = ~0ull;
        if (i < P) {
            unsigned long long m = mrec[i];
            int y = (int)(m & 0xFFFFFFFFull);
            float w  = mono2f((unsigned)(m >> 32));
            float bf = mono2f(bval[y]);
            float b, d;
            if (which == 0) { b = bf; d = w; }
            else            { b = -w; d = -bf; }
            pb[i] = b; pdd[i] = d;
            unsigned pm = __float_as_uint(d - b);   // pers > 0 -> monotone bits
            kk2 = ((unsigned long long)(~pm) << 32) | (unsigned)i;
        }
        e2[i] = kk2;
    }
    if (tid < NMAXP) rsel[tid] = -1;
    __syncthreads();

    // ---- top-NMAXP by rank-by-count ----
    const int off = (which == 0) ? 1 : 0;          // H0 slot 0 = essential pair
    for (int i = tid; i < P64; i += NTH) {
        unsigned long long ki = e2[i];
        int rk = rankOf(e2, P64, ki);
        if (i < P && rk < NMAXP - off) rsel[rk + off] = i;
    }
    __syncthreads();

    // ---- write diagram: [32, 2, 100, 2] ----
    float* o = out + (size_t)blk * NMAXP * 2;
    if (tid < NMAXP) {
        float b = 0.f, d = 0.f;
        if (which == 0 && tid == 0) { b = mono2f(bval[0]); d = ESS_DEATH; }
        else {
            int q = rsel[tid];
            if (q >= 0) { b = pb[q]; d = pdd[q]; }
        }
        o[tid * 2]     = b;
        o[tid * 2 + 1] = d;
    }
}

extern "C" void kernel_launch(void* const* d_in, const int* in_sizes, int n_in,
                              void* d_out, int out_size, void* d_ws, size_t ws_size,
                              hipStream_t stream) {
    (void)in_sizes; (void)n_in; (void)out_size; (void)d_ws; (void)ws_size;
    const float* x = (const float*)d_in[0];
    float* out = (float*)d_out;
    pd_kernel<<<dim3(64), dim3(NTH), 0, stream>>>(x, out);
}

// Round 5
// 80.039 us; speedup vs baseline: 1.4019x; 1.2189x over previous
//
#include <hip/hip_runtime.h>
#include <math.h>

#define HH 28
#define WW 28
#define NPIX 784
#define MMAX 785
#define NMAXP 100
#define NTH 1024
#define BCAP 512       // max basins (theory bound: H1 4-conn <= 393)
#define HSZ 2048
#define HMASK 2047
#define ECAP 2048      // deduped basin-pair edges (random ~470); max survivors = HSZ
#define PCAP 512
#define JMAXP 10       // 2^10 >= 785 worst-case descent depth
#define NBUCK 4096     // 12-bit weight buckets for the edge sort (= 2*HSZ, aliases hash)
// Essential-death sentinel: must stay FINITE after the harness's bf16
// round-trip (FLT_MAX rounds to +inf in bf16 -> inf-inf=NaN). 1e30 is safe.
#define ESS_DEATH 1e30f

template<int N> struct IC { static constexpr int v = N; };

// monotone float<->u32 (totally ordered as unsigned)
__device__ __forceinline__ unsigned f2mono(float f) {
    unsigned u = __float_as_uint(f);
    return (u & 0x80000000u) ? ~u : (u | 0x80000000u);
}
__device__ __forceinline__ float mono2f(unsigned m) {
    unsigned u = (m & 0x80000000u) ? (m ^ 0x80000000u) : ~m;
    return __uint_as_float(u);
}

// neighbors of cell c; nb[k] = -1 if invalid.
// which==0: 8-conn. which==1: 4-conn + virtual boundary node NPIX.
__device__ __forceinline__ int get_nbrs(int c, int which, int* nb) {
    int ci = c / WW;
    int cj = c - ci * WW;
    if (which == 0) {
        const int di[8] = {-1,-1,-1, 0, 0, 1, 1, 1};
        const int dj[8] = {-1, 0, 1,-1, 1,-1, 0, 1};
        #pragma unroll
        for (int k = 0; k < 8; ++k) {
            int ii = ci + di[k], jj = cj + dj[k];
            nb[k] = (ii >= 0 && ii < HH && jj >= 0 && jj < WW) ? (ii * WW + jj) : -1;
        }
        return 8;
    } else {
        const int di[4] = {-1, 1, 0, 0};
        const int dj[4] = { 0, 0,-1, 1};
        #pragma unroll
        for (int k = 0; k < 4; ++k) {
            int ii = ci + di[k], jj = cj + dj[k];
            nb[k] = (ii >= 0 && ii < HH && jj >= 0 && jj < WW) ? (ii * WW + jj) : -1;
        }
        nb[4] = (ci == 0 || ci == HH - 1 || cj == 0 || cj == WW - 1) ? NPIX : -1;
        return 5;
    }
}

// One block per (sample, dim): blk = s*2 + which.
// which==0 -> H0 (8-conn sublevel on x); which==1 -> H1 via superlevel
// (sublevel on -x, 4-conn, virtual -inf boundary node).
__global__ __launch_bounds__(NTH)
void pd_kernel(const float* __restrict__ x, float* __restrict__ out)
{
    const int blk   = blockIdx.x;
    const int s     = blk >> 1;
    const int which = blk & 1;
    const int tid   = threadIdx.x;
    const int lane  = tid & 63;
    const int M     = NPIX + which;

    __shared__ float vals[MMAX];
    __shared__ int   dA[MMAX];                  // descent ptr (ping); later R1 minF/dd
    __shared__ int   dB[MMAX];                  // ptr (pong); later R1 alive-ancestor dd2
    __shared__ int   cido[MMAX];                // per-cell compact basin id
    __shared__ unsigned long long rootsU[BCAP]; // unsorted (valmono<<32)|cell, 64-padded
    __shared__ unsigned bval[BCAP];             // basin-min valmono per cid (= value rank)
    __shared__ unsigned hpool[2 * HSZ];         // hash key|val; reused as sort cnt[NBUCK]
    __shared__ unsigned long long e2[ECAP];     // unsorted edges; then SORTED; then sel keys
    __shared__ unsigned long long e3[ECAP];     // bucket-grouped scratch
    __shared__ unsigned long long mrec[PCAP];   // merge records (wmono<<32)|y (order free)
    __shared__ float pb[PCAP], pdd[PCAP];       // recorded pairs (output space)
    __shared__ int   rsel[NMAXP];               // output slot -> pair index
    __shared__ int   bcnt, scnt, npairs, np0g;
    __shared__ int   jflag[JMAXP + 1];
    __shared__ int   wtot[NTH / 64], wbase2[NTH / 64];

    unsigned* const hkey = hpool;               // hash: pk+1 (0 = empty)
    unsigned* const hval = hpool + HSZ;         // hash: min weight (monotone u32)
    unsigned* const cnt  = hpool;               // sort: NBUCK bucket counters (hash is dead)

    // rank of ki among arr[0..N64) (N64 = 64-multiple, padded with ~0ull;
    // distinct keys). Chunked: wave loads 64 keys coalesced, broadcasts via
    // readlane (unrolled -> constant lane), counts kjj < ki. No barriers.
    auto rankOf = [&](const unsigned long long* arr, int N64,
                      unsigned long long ki) -> int {
        int rk = 0;
        for (int base = 0; base < N64; base += 64) {
            unsigned long long kj = arr[base + lane];
            unsigned lo = (unsigned)kj, hi = (unsigned)(kj >> 32);
            #pragma unroll
            for (int t = 0; t < 64; ++t) {
                unsigned jlo = (unsigned)__builtin_amdgcn_readlane((int)lo, t);
                unsigned jhi = (unsigned)__builtin_amdgcn_readlane((int)hi, t);
                unsigned long long kjj = ((unsigned long long)jhi << 32) | jlo;
                rk += (kjj < ki) ? 1 : 0;
            }
        }
        return rk;
    };

    if (tid == 0) { bcnt = 0; scnt = 0; npairs = 0; np0g = 0; }
    if (tid < JMAXP + 1) jflag[tid] = 0;
    for (int i = tid; i < HSZ; i += NTH) { hkey[i] = 0u; hval[i] = 0xFFFFFFFFu; }
    for (int i = tid; i < NPIX; i += NTH) {
        float v = x[s * NPIX + i];
        vals[i] = which ? -v : v;
    }
    if (tid == 0 && which) vals[NPIX] = -INFINITY;
    __syncthreads();

    // ---- descent (lex-min over {self} U nbrs) + fused root collection ----
    // NTH=1024 >= M: exactly one cell per thread.
    unsigned long long rku = 0ull;
    int rc = 0;
    if (tid < M) {
        int i = tid;
        int best = i; float bv = vals[i];
        if (i < NPIX) {
            int nb[8];
            int K = get_nbrs(i, which, nb);
            for (int k = 0; k < K; ++k) {
                int n = nb[k]; if (n < 0) continue;
                float vn = vals[n];
                if (vn < bv || (vn == bv && n < best)) { bv = vn; best = n; }
            }
        }
        dA[i] = best;
        if (best == i) {
            rku = ((unsigned long long)f2mono(vals[i]) << 32) | (unsigned)i;
            rc = 1;
        }
    }
    {   // wave inclusive scan of rc -> one atomic per wave
        int sc = rc;
        #pragma unroll
        for (int d = 1; d < 64; d <<= 1) {
            int up = __shfl_up(sc, d, 64);
            if (lane >= d) sc += up;
        }
        int wtotal = __shfl(sc, 63, 64);
        int base = 0;
        if (lane == 0 && wtotal) base = atomicAdd(&bcnt, wtotal);
        base = __shfl(base, 0, 64);
        int off = base + sc - rc;
        if (rc && off < BCAP) rootsU[off] = rku;
    }
    __syncthreads();

    int B = bcnt; if (B > BCAP) B = BCAP;
    const int B64 = (B + 63) & ~63;
    // pad rootsU inside the first jumping phase (read only after next barrier)
    for (int i = B + tid; i < B64; i += NTH) rootsU[i] = ~0ull;

    // ---- pointer jumping: ping-pong doubling with exact early exit ----
    int* rootArr = dA;
    {
        int* src = dA;
        int* dst = dB;
        for (int pass = 0; pass < JMAXP; ++pass) {
            bool changed = false;
            for (int i = tid; i < M; i += NTH) {
                int q0 = src[i];
                int q1 = src[q0];
                dst[i] = q1;
                changed |= (q1 != q0);
            }
            unsigned long long mk = __ballot(changed);
            if (lane == 0 && mk) jflag[pass] = 1;   // benign race: all store 1
            __syncthreads();
            rootArr = dst;
            if (!jflag[pass]) break;
            int* tmp = src; src = dst; dst = tmp;
        }
    }
    int* cidmap = (rootArr == dA) ? dB : dA;   // scratch that won't clobber rootArr

    // ---- cid = value rank of root (rank-by-count) ----
    for (int i = tid; i < B64; i += NTH) {
        unsigned long long ki = rootsU[i];
        int rk = rankOf(rootsU, B64, ki);
        if (i < B) {
            int cell = (int)(ki & 0xFFFFFFFFull);
            cidmap[cell] = rk;
            bval[rk] = (unsigned)(ki >> 32);
        }
    }
    __syncthreads();
    for (int i = tid; i < M; i += NTH) cido[i] = cidmap[rootArr[i]];
    __syncthreads();
    // dA/dB are dead from here on -> reused by round-1 elimination:
    int* const minF = dA;        // [0..255] first-sorted-edge index per basin
    int* const ddp  = dA + 256;  // [0..255] died-into pointer (identity = alive)
    int* const dd2  = dB;        // [0..255] alive ancestor after chase

    // ---- cross-basin edges -> hash dedup (min weight per basin pair) ----
    for (int c = tid; c < NPIX; c += NTH) {
        float vc = vals[c];
        int bc = cido[c];
        int nb[8];
        int K = get_nbrs(c, which, nb);
        unsigned wm = f2mono(vc);
        for (int k = 0; k < K; ++k) {
            int n = nb[k]; if (n < 0) continue;
            float vn = vals[n];
            if (!(vn < vc || (vn == vc && n < c))) continue;  // emit from higher endpoint
            int bn = cido[n];
            if (bn == bc) continue;
            unsigned c0 = (unsigned)(bc < bn ? bc : bn);
            unsigned c1 = (unsigned)(bc < bn ? bn : bc);
            unsigned pk  = (c0 << 9) | c1;       // cids < 512 -> 18 bits
            unsigned key = pk + 1u;
            unsigned slot = (pk * 0x9E3779B1u) >> 21;  // 11-bit hash
            for (;;) {
                unsigned prev = atomicCAS(&hkey[slot], 0u, key);
                if (prev == 0u || prev == key) { atomicMin(&hval[slot], wm); break; }
                slot = (slot + 1) & HMASK;
            }
        }
    }
    __syncthreads();

    // ---- gather survivors: 2 slots/thread, wave scan, 1 atomic/wave ----
    {
        unsigned k0 = hkey[tid], k1 = hkey[tid + NTH];
        unsigned v0 = hval[tid], v1 = hval[tid + NTH];
        int c = (k0 ? 1 : 0) + (k1 ? 1 : 0);
        int sc = c;
        #pragma unroll
        for (int d = 1; d < 64; d <<= 1) {
            int up = __shfl_up(sc, d, 64);
            if (lane >= d) sc += up;
        }
        int wtotal = __shfl(sc, 63, 64);
        int base = 0;
        if (lane == 0 && wtotal) base = atomicAdd(&scnt, wtotal);
        base = __shfl(base, 0, 64);
        int p = base + sc - c;
        if (k0) { e2[p] = ((unsigned long long)v0 << 18) | (unsigned long long)(k0 - 1u); ++p; }
        if (k1) { e2[p] = ((unsigned long long)v1 << 18) | (unsigned long long)(k1 - 1u); ++p; }
    }
    __syncthreads();
    const int S = scnt;                          // <= HSZ = ECAP, no overflow
    const int S64 = (S + 63) & ~63;

    // ---- deterministic bucket sort by weight (O(S) passes) ----
    // bucket = top 12 bits of wmono = key >> 38. count -> exclusive prefix ->
    // grouped scatter (atomic order) -> exact in-bucket rank on full 64-bit
    // keys (distinct -> order independent of atomic timing) -> sorted e2.
    for (int i = tid; i < NBUCK; i += NTH) cnt[i] = 0u;   // hash is dead; reuse
    for (int i = S + tid; i < S64; i += NTH) { e2[i] = ~0ull; e3[i] = ~0ull; }
    __syncthreads();
    for (int i = tid; i < S; i += NTH)
        atomicAdd(&cnt[(unsigned)(e2[i] >> 38)], 1u);
    __syncthreads();
    {   // exclusive prefix over NBUCK bins: 4/thread local + shfl wave scan
        unsigned c[4]; int loc = 0;
        #pragma unroll
        for (int k2 = 0; k2 < 4; ++k2) { c[k2] = cnt[tid * 4 + k2]; loc += (int)c[k2]; }
        int scan = loc;
        #pragma unroll
        for (int d = 1; d < 64; d <<= 1) {
            int up = __shfl_up(scan, d, 64);
            if (lane >= d) scan += up;
        }
        int wid = tid >> 6;
        if (lane == 63) wtot[wid] = scan;
        __syncthreads();
        if (tid == 0) {
            int acc = 0;
            #pragma unroll
            for (int w2 = 0; w2 < NTH / 64; ++w2) { wbase2[w2] = acc; acc += wtot[w2]; }
        }
        __syncthreads();
        int ex = wbase2[wid] + (scan - loc);
        #pragma unroll
        for (int k2 = 0; k2 < 4; ++k2) { cnt[tid * 4 + k2] = (unsigned)ex; ex += (int)c[k2]; }
    }
    __syncthreads();
    for (int i = tid; i < S; i += NTH) {
        unsigned long long k = e2[i];
        unsigned slot = atomicAdd(&cnt[(unsigned)(k >> 38)], 1u);
        e3[slot] = k;
    }
    __syncthreads();
    // after scatter: bucket b spans [cnt[b-1], cnt[b]) (cnt[-1] = 0)
    for (int i = tid; i < S; i += NTH) {
        unsigned long long ki = e3[i];
        int b = (int)(ki >> 38);
        int lo2 = (b == 0) ? 0 : (int)cnt[b - 1];
        int hi2 = (int)cnt[b];
        int rk = lo2;
        for (int j = lo2; j < hi2; ++j) rk += (e3[j] < ki) ? 1 : 0;
        e2[rk] = ki;
    }
    // also init round-1 arrays (dA region is dead; no reader until after barrier)
    if (tid < 256) { minF[tid] = 0x7FFFFFFF; ddp[tid] = tid; }
    __syncthreads();

    // ---- ROUND-1 basin elimination (exact, parallel) ----
    // For basin y, its first sorted incident edge e=(y,z,w): if z older (z<y),
    // serial Kruskal provably kills y at e (comp(y)={y} there, since e is y's
    // min edge and weights below never touch y). Emit pair, mark y died->z.
    // Residual Kruskal replays all edges from pre-merged labels; dead basins
    // contribute no lighter edges, so component structure at every threshold
    // is identical => pairing identical.
    const bool doR1 = (B <= 256) && (S > 0);
    if (doR1) {
        for (int i = tid; i < S; i += NTH) {
            unsigned pk = (unsigned)e2[i] & 0x3FFFFu;
            atomicMin(&minF[pk >> 9], i);
            atomicMin(&minF[pk & 511u], i);
        }
    }
    __syncthreads();
    if (doR1) {
        for (int y = tid; y < B; y += NTH) {
            int fi = minF[y];
            if (fi != 0x7FFFFFFF) {
                unsigned long long k = e2[fi];
                unsigned pk = (unsigned)k & 0x3FFFFu;
                int a = (int)(pk >> 9), bq = (int)(pk & 511u);
                int z = (a == y) ? bq : a;
                if (z < y) {   // partner older -> y dies here
                    unsigned wm = (unsigned)(k >> 18);
                    int slot = atomicAdd(&np0g, 1);
                    if (slot < PCAP)
                        mrec[slot] = ((unsigned long long)wm << 32) | (unsigned)y;
                    ddp[y] = z;
                }
            }
        }
    }
    __syncthreads();
    if (doR1) {
        for (int y = tid; y < 256; y += NTH) {   // chase died-into chain to alive root
            int r = ddp[y];
            int r2 = ddp[r];
            while (r2 != r) { r = r2; r2 = ddp[r]; }
            dd2[y] = r;
        }
    }
    __syncthreads();

    // ---- serial Kruskal on wave 0 (reads SORTED e2) ----
    // B <= 256 fast path: labels byte-PACKED, one 32-bit reg/lane
    // (byte j = label of basin j*64+lane), INITIALIZED from round-1 alive
    // ancestors (dead basins pre-merged; their edges become internal and are
    // dropped by the prefilter). np starts at round-1's pair count.
    auto kruskalP = [&]() {
        unsigned pl = ((unsigned)dd2[tid]) | ((unsigned)dd2[64 + tid] << 8)
                    | ((unsigned)dd2[128 + tid] << 16) | ((unsigned)dd2[192 + tid] << 24);
        int np = np0g;
        const int target = B - 1;
        for (int base = 0; base < S && np < target; base += 64) {
            unsigned long long ecache = e2[base + tid];      // base mult of 64, tid<64
            unsigned eklo = (unsigned)ecache;
            unsigned ehiw = (unsigned)(ecache >> 32);
            unsigned pkL  = eklo & 0x3FFFFu;
            unsigned raaL = pkL >> 9, rbbL = pkL & 511u;     // < 256 here
            int bpa = __builtin_amdgcn_ds_bpermute((int)((raaL & 63u) << 2), (int)pl);
            int bpb = __builtin_amdgcn_ds_bpermute((int)((rbbL & 63u) << 2), (int)pl);
            unsigned la0 = ((unsigned)bpa >> ((raaL >> 6) * 8)) & 0xFFu;
            unsigned lb0 = ((unsigned)bpb >> ((rbbL >> 6) * 8)) & 0xFFu;
            bool isc = ((base + tid) < S) && (la0 != lb0);
            unsigned long long m = __ballot(isc);
            while (m != 0ull && np < target) {
                unsigned klo[4]; int lnt[4]; unsigned la[4], lb[4]; bool act[4];
                #pragma unroll
                for (int t = 0; t < 4; ++t) {
                    act[t] = (m != 0ull);
                    int ln = act[t] ? (int)__builtin_ctzll(m) : 0;
                    if (act[t]) m &= (m - 1ull);
                    lnt[t] = ln;
                    klo[t] = (unsigned)__builtin_amdgcn_readlane((int)eklo, ln);
                    unsigned pk  = klo[t] & 0x3FFFFu;
                    unsigned raa = pk >> 9, rbb = pk & 511u;  // uniform scalars
                    unsigned kra = (unsigned)__builtin_amdgcn_readlane((int)pl, (int)(raa & 63u));
                    unsigned krb = (unsigned)__builtin_amdgcn_readlane((int)pl, (int)(rbb & 63u));
                    la[t] = (kra >> ((raa >> 6) * 8)) & 0xFFu;   // uniform -> SALU
                    lb[t] = (krb >> ((rbb >> 6) * 8)) & 0xFFu;
                    if (!act[t]) { la[t] = 0; lb[t] = 0; }       // no-op slot
                }
                unsigned ys[4], es[4];
                #pragma unroll
                for (int t = 0; t < 4; ++t) {
                    unsigned A = la[t], Bv = lb[t];
                    #pragma unroll
                    for (int k = 0; k < t; ++k) {
                        A  = (A  == ys[k]) ? es[k] : A;
                        Bv = (Bv == ys[k]) ? es[k] : Bv;
                    }
                    unsigned mn = A < Bv ? A : Bv;
                    unsigned mx = A ^ Bv ^ mn;
                    es[t] = mn;
                    ys[t] = (A != Bv) ? mx : 0xFFFFFFFFu;   // sentinel: no merge
                }
                #pragma unroll
                for (int t = 0; t < 4; ++t) {
                    if (ys[t] != 0xFFFFFFFFu) {
                        unsigned khit = (unsigned)__builtin_amdgcn_readlane(
                            (int)ehiw, lnt[t]);
                        unsigned w = (klo[t] >> 18) | (khit << 14);
                        if (tid == 0 && np < PCAP)
                            mrec[np] = ((unsigned long long)w << 32)
                                     | (unsigned long long)ys[t];
                        ++np;
                        // packed byte replace: bytes of pl equal to y -> e
                        unsigned yr  = ys[t] * 0x01010101u;
                        unsigned xr  = (ys[t] ^ es[t]) * 0x01010101u;
                        unsigned mm  = pl ^ yr;                          // 0-byte = match
                        unsigned nz  = ((mm & 0x7F7F7F7Fu) + 0x7F7F7F7Fu) | mm;
                        unsigned tz  = ~nz & 0x80808080u;                // 0x80 at matches
                        unsigned msk = tz | (tz - (tz >> 7));            // 0xFF at matches
                        pl ^= (xr & msk);
                    }
                }
            }
        }
        if (tid == 0) npairs = (np < PCAP) ? np : PCAP;
    };

    // fallback for 256 < B <= 512: striped labels in 8 regs (no round-1)
    auto kruskal = [&](auto icreg) {
        constexpr int NREG = decltype(icreg)::v;
        int lab[NREG];
        #pragma unroll
        for (int r = 0; r < NREG; ++r) lab[r] = r * 64 + tid;
        int np = 0;
        const int target = B - 1;
        for (int base = 0; base < S && np < target; base += 64) {
            unsigned long long ecache = e2[base + tid];
            unsigned eklo = (unsigned)ecache;
            unsigned ehiw = (unsigned)(ecache >> 32);
            unsigned pkL  = eklo & 0x3FFFFu;
            unsigned raaL = pkL >> 9, rbbL = pkL & 511u;
            int bpa[NREG], bpb[NREG];
            int aA = (int)((raaL & 63u) << 2);
            int aB = (int)((rbbL & 63u) << 2);
            #pragma unroll
            for (int r = 0; r < NREG; ++r) {
                bpa[r] = __builtin_amdgcn_ds_bpermute(aA, lab[r]);
                bpb[r] = __builtin_amdgcn_ds_bpermute(aB, lab[r]);
            }
            int la0, lb0;
            {
                unsigned sA = raaL >> 6, sB = rbbL >> 6;
                int x0 = (sA & 1) ? bpa[1] : bpa[0];
                int x1 = (sA & 1) ? bpa[3] : bpa[2];
                int x2 = (sA & 1) ? bpa[5] : bpa[4];
                int x3 = (sA & 1) ? bpa[7] : bpa[6];
                int x4 = (sA & 2) ? x1 : x0;
                int x5 = (sA & 2) ? x3 : x2;
                la0 = (sA & 4) ? x5 : x4;
                int y0 = (sB & 1) ? bpb[1] : bpb[0];
                int y1 = (sB & 1) ? bpb[3] : bpb[2];
                int y2 = (sB & 1) ? bpb[5] : bpb[4];
                int y3 = (sB & 1) ? bpb[7] : bpb[6];
                int y4 = (sB & 2) ? y1 : y0;
                int y5 = (sB & 2) ? y3 : y2;
                lb0 = (sB & 4) ? y5 : y4;
            }
            bool isc = ((base + tid) < S) && (la0 != lb0);
            unsigned long long m = __ballot(isc);
            while (m != 0ull && np < target) {
                unsigned klo[4]; int lnt[4], la[4], lb[4]; bool act[4];
                #pragma unroll
                for (int t = 0; t < 4; ++t) {
                    act[t] = (m != 0ull);
                    int ln = act[t] ? (int)__builtin_ctzll(m) : 0;
                    if (act[t]) m &= (m - 1ull);
                    lnt[t] = ln;
                    klo[t] = (unsigned)__builtin_amdgcn_readlane((int)eklo, ln);
                    unsigned pk  = klo[t] & 0x3FFFFu;
                    unsigned raa = pk >> 9, rbb = pk & 511u;
                    int sa = (int)(raa >> 6), sb = (int)(rbb >> 6);
                    asm volatile("" : "+v"(sa), "+v"(sb));   // force cndmask tree
                    int a1 = (sa & 1) ? lab[1] : lab[0];
                    int b1 = (sa & 1) ? lab[3] : lab[2];
                    int c1 = (sa & 1) ? lab[5] : lab[4];
                    int d1 = (sa & 1) ? lab[7] : lab[6];
                    int e1 = (sa & 2) ? b1 : a1;
                    int f1 = (sa & 2) ? d1 : c1;
                    int g1 = (sa & 4) ? f1 : e1;
                    int a2 = (sb & 1) ? lab[1] : lab[0];
                    int b2 = (sb & 1) ? lab[3] : lab[2];
                    int c2 = (sb & 1) ? lab[5] : lab[4];
                    int d2 = (sb & 1) ? lab[7] : lab[6];
                    int e2v = (sb & 2) ? b2 : a2;
                    int f2 = (sb & 2) ? d2 : c2;
                    int g2 = (sb & 4) ? f2 : e2v;
                    la[t] = __builtin_amdgcn_readlane(g1, (int)(raa & 63u));
                    lb[t] = __builtin_amdgcn_readlane(g2, (int)(rbb & 63u));
                    if (!act[t]) { la[t] = 0; lb[t] = 0; }
                }
                int ys[4], es[4];
                #pragma unroll
                for (int t = 0; t < 4; ++t) {
                    int A = la[t], Bv = lb[t];
                    #pragma unroll
                    for (int k = 0; k < t; ++k) {
                        A  = (A  == ys[k]) ? es[k] : A;
                        Bv = (Bv == ys[k]) ? es[k] : Bv;
                    }
                    int mn = A < Bv ? A : Bv;
                    int mx = A ^ Bv ^ mn;
                    es[t] = mn;
                    ys[t] = (A != Bv) ? mx : -1;
                }
                #pragma unroll
                for (int t = 0; t < 4; ++t) {
                    if (ys[t] >= 0) {
                        unsigned khit = (unsigned)__builtin_amdgcn_readlane(
                            (int)ehiw, lnt[t]);
                        unsigned w = (klo[t] >> 18) | (khit << 14);
                        if (tid == 0 && np < PCAP)
                            mrec[np] = ((unsigned long long)w << 32) | (unsigned)ys[t];
                        ++np;
                        #pragma unroll
                        for (int r = 0; r < NREG; ++r)
                            lab[r] = (lab[r] == ys[t]) ? es[t] : lab[r];
                    }
                }
            }
        }
        if (tid == 0) npairs = (np < PCAP) ? np : PCAP;
    };

    if (tid < 64 && S > 0) {
        if (B <= 256) kruskalP();
        else          kruskal(IC<8>{});
    }
    __syncthreads();
    const int P = npairs;
    const int P64 = (P + 63) & ~63;

    // ---- materialize pairs + build selection keys (pers desc, idx asc) ----
    for (int i = tid; i < P64; i += NTH) {
        unsigned long long kk2 = ~0ull;
        if (i < P) {
            unsigned long long m = mrec[i];
            int y = (int)(m & 0xFFFFFFFFull);
            float w  = mono2f((unsigned)(m >> 32));
            float bf = mono2f(bval[y]);
            float b, d;
            if (which == 0) { b = bf; d = w; }
            else            { b = -w; d = -bf; }
            pb[i] = b; pdd[i] = d;
            unsigned pm = __float_as_uint(d - b);   // pers > 0 -> monotone bits
            kk2 = ((unsigned long long)(~pm) << 32) | (unsigned)i;
        }
        e2[i] = kk2;
    }
    if (tid < NMAXP) rsel[tid] = -1;
    __syncthreads();

    // ---- top-NMAXP by rank-by-count ----
    const int off = (which == 0) ? 1 : 0;          // H0 slot 0 = essential pair
    for (int i = tid; i < P64; i += NTH) {
        unsigned long long ki = e2[i];
        int rk = rankOf(e2, P64, ki);
        if (i < P && rk < NMAXP - off) rsel[rk + off] = i;
    }
    __syncthreads();

    // ---- write diagram: [32, 2, 100, 2] ----
    float* o = out + (size_t)blk * NMAXP * 2;
    if (tid < NMAXP) {
        float b = 0.f, d = 0.f;
        if (which == 0 && tid == 0) { b = mono2f(bval[0]); d = ESS_DEATH; }
        else {
            int q = rsel[tid];
            if (q >= 0) { b = pb[q]; d = pdd[q]; }
        }
        o[tid * 2]     = b;
        o[tid * 2 + 1] = d;
    }
}

extern "C" void kernel_launch(void* const* d_in, const int* in_sizes, int n_in,
                              void* d_out, int out_size, void* d_ws, size_t ws_size,
                              hipStream_t stream) {
    (void)in_sizes; (void)n_in; (void)out_size; (void)d_ws; (void)ws_size;
    const float* x = (const float*)d_in[0];
    float* out = (float*)d_out;
    pd_kernel<<<dim3(64), dim3(NTH), 0, stream>>>(x, out);
}